// Round 4
// baseline (553.046 us; speedup 1.0000x reference)
//
#include <hip/hip_runtime.h>

// Capsule dynamic routing — b-on-lanes / o-on-waves, VECTOR-path weights.
// u_i:(B,N,DI) f32, w:(1,N,NO,DI,DE) f32, bias:(N,NO,1) f32, r=3.
// Identity: logits_r = u_ji . vsum (vsum = running sum of v; u_ji includes
// bias so the bias term folds in).
// R10 theory: R1/R2/R3 all stall ~10K cy per n-step because weight delivery
//   goes through a skinny per-CU shared pipe: scalar K$ (R1/R2: 8 s_load
//   lines/n/wave, streaming misses, few MSHRs) or LDS broadcast (R3: 32
//   ds_read_b128/n/wave). Fix: same-address broadcast loads on the VECTOR
//   path — launder the wave-uniform weight pointer into an opaque VGPR so
//   the compiler emits global_load_dwordx4 (1 L1 line request, broadcast,
//   counted vmcnt, pipelined across unrolled d). Bias prefetched the same
//   way. Everything else = R2 (best so far, 43 us/launch).

#define B    256
#define N    1152
#define NO   10
#define DI   8
#define DE   16
#define NTILE   8
#define NTILES  144    // N / NTILE
#define BG      64     // b per block (= lanes per wave)
#define BGS     4      // B / BG
#define THREADS 640    // 10 waves, o = wave id

// ws layout (floats)
#define SP_OFF 0
#define SP_SZ  (NTILES * B * NO * DE)   // 5,898,240
#define VS_OFF (SP_OFF + SP_SZ)
#define VS_SZ  (B * NO * DE)            // 40,960
#define UT_OFF (VS_OFF + VS_SZ)
#define UT_SZ  (2 * N * B * 4)          // 2,359,296 (= B*N*DI)

// ---------------------------------------------------------------------------
// One-time transpose: u (B,N,8) -> ut[((n*2+h)*B + b)*4 + j] = u[b][n][h*4+j]
// ---------------------------------------------------------------------------
__global__ __launch_bounds__(256)
void transpose_kernel(const float* __restrict__ u, float* __restrict__ ut) {
    const int lane = threadIdx.x & 63;
    const int wv   = threadIdx.x >> 6;           // 0..3 -> n offset
    const int n    = blockIdx.x * 4 + wv;
    const int b    = blockIdx.y * 64 + lane;
    const float* up = u + ((size_t)b * N + n) * DI;
    const float4 a0 = *(const float4*)up;
    const float4 a1 = *(const float4*)(up + 4);
    *(float4*)(ut + ((size_t)(n * 2 + 0) * B + b) * 4) = a0;
    *(float4*)(ut + ((size_t)(n * 2 + 1) * B + b) * 4) = a1;
}

// ---------------------------------------------------------------------------
// Routing pass. Grid: (144 n-tiles, 4 b-groups) x 640 threads (10 waves).
// ---------------------------------------------------------------------------
__global__ __launch_bounds__(THREADS, 6)
void routing_kernel(const float* __restrict__ u,
                    const float* __restrict__ ut,
                    const float* __restrict__ w,
                    const float* __restrict__ bias,
                    const float* __restrict__ vsum,
                    float* __restrict__ s_part,
                    const int has_v,
                    const int use_ut) {
    __shared__ float lgx[2][NO][BG];            // 5 KB double-buffered exchange
    const int tid  = threadIdx.x;
    const int lane = tid & 63;
    const int wv   = __builtin_amdgcn_readfirstlane(tid >> 6);  // 0..9, uniform
    const int o    = wv;                         // one output capsule per wave
    const int b    = blockIdx.y * BG + lane;
    const int n0   = blockIdx.x * NTILE;

    // Bias for this wave's o, all 8 n of the tile — broadcast vector loads,
    // hoisted out of the n loop (keeps them off the per-n critical chain).
    const float* bp = bias + n0 * NO + o;
    asm volatile("" : "+v"(bp));                 // opaque -> vector path
    float bvs[NTILE];
#pragma unroll
    for (int i = 0; i < NTILE; ++i)
        bvs[i] = bp[i * NO];

    // vsum fragment for this thread's (b, o), full e — loop-invariant
    float4 vv[4];
#pragma unroll
    for (int eq = 0; eq < 4; ++eq)
        vv[eq] = make_float4(0.f, 0.f, 0.f, 0.f);
    if (has_v) {
#pragma unroll
        for (int eq = 0; eq < 4; ++eq)
            vv[eq] = *(const float4*)(vsum + ((size_t)b * NO + o) * DE + eq * 4);
    }

    float4 acc[4];
#pragma unroll
    for (int eq = 0; eq < 4; ++eq)
        acc[eq] = make_float4(0.f, 0.f, 0.f, 0.f);

    for (int i = 0; i < NTILE; ++i) {
        const int n = n0 + i;

        // u row for lane's b — coalesced from ut (1KB/wave/instr), or legacy gather
        float4 u0, u1;
        if (use_ut) {
            const float* up = ut + ((size_t)(n * 2) * B + b) * 4;
            u0 = *(const float4*)up;
            u1 = *(const float4*)(up + B * 4);
        } else {
            const float* up = u + ((size_t)b * N + n) * DI;
            u0 = *(const float4*)up;
            u1 = *(const float4*)(up + 4);
        }
        const float ur[DI] = {u0.x, u0.y, u0.z, u0.w, u1.x, u1.y, u1.z, u1.w};

        // u_ji for this wave's o, all 16 e. Weights via BROADCAST vector
        // loads: laundered base pointer (opaque VGPR) + immediate offsets ->
        // global_load_dwordx4, 1 L1 line request each, vmcnt-pipelined.
        const float* wp = w + ((size_t)n * NO + o) * (DI * DE);
        asm volatile("" : "+v"(wp));             // opaque -> vector path
        const float bv = bvs[i];
        float4 uji[4];
#pragma unroll
        for (int eq = 0; eq < 4; ++eq)
            uji[eq] = make_float4(bv, bv, bv, bv);
#pragma unroll
        for (int d = 0; d < DI; ++d) {
#pragma unroll
            for (int eq = 0; eq < 4; ++eq) {
                const float4 w4 = *(const float4*)(wp + d * DE + eq * 4);
                uji[eq].x += ur[d] * w4.x;
                uji[eq].y += ur[d] * w4.y;
                uji[eq].z += ur[d] * w4.z;
                uji[eq].w += ur[d] * w4.w;
            }
        }

        float c;
        if (has_v) {
            const int pb = i & 1;
            // logit: full-e dot in-thread, exchange via LDS for the softmax
            float lg = 0.f;
#pragma unroll
            for (int eq = 0; eq < 4; ++eq)
                lg += uji[eq].x * vv[eq].x + uji[eq].y * vv[eq].y
                    + uji[eq].z * vv[eq].z + uji[eq].w * vv[eq].w;
            lgx[pb][o][lane] = lg;
            __syncthreads();
            float l[NO];
#pragma unroll
            for (int oo = 0; oo < NO; ++oo) l[oo] = lgx[pb][oo][lane];
            // no second barrier: buffer pb is next written at iter i+2, which
            // is separated from these reads by the barrier at iter i+1.

            float m = l[0];
#pragma unroll
            for (int oo = 1; oo < NO; ++oo) m = fmaxf(m, l[oo]);
            float sum = 0.f;
#pragma unroll
            for (int oo = 0; oo < NO; ++oo) { l[oo] = __expf(l[oo] - m); sum += l[oo]; }
            c = l[o] / sum;
        } else {
            c = 0.1f;   // softmax of zeros
        }

#pragma unroll
        for (int eq = 0; eq < 4; ++eq) {
            acc[eq].x += c * uji[eq].x;
            acc[eq].y += c * uji[eq].y;
            acc[eq].z += c * uji[eq].z;
            acc[eq].w += c * uji[eq].w;
        }
    }

    // s_part[tile][b][o][e] — same layout squash already expects
    float* sp = s_part + (((size_t)blockIdx.x * B + b) * NO + o) * DE;
#pragma unroll
    for (int eq = 0; eq < 4; ++eq)
        *(float4*)(sp + eq * 4) = acc[eq];
}

// ---------------------------------------------------------------------------
// Squash (unchanged — proven): s = sum_tiles s_part;
// v = ||s||/(1+||s||^2)*s; out = v; vsum += v. 4 threads/element (36 tiles ea).
// ---------------------------------------------------------------------------
__global__ __launch_bounds__(256)
void squash_kernel(const float* __restrict__ s_part,
                   float* __restrict__ vsum,
                   float* __restrict__ out,
                   const int accum) {
    const int t0 = blockIdx.x * 256 + threadIdx.x;   // < 4*40960
    const int q  = t0 & 3;
    const int g  = t0 >> 2;

    float s = 0.f;
    const float* sp = s_part + (size_t)(q * 36) * (B * NO * DE) + g;
#pragma unroll 9
    for (int i = 0; i < 36; ++i)
        s += sp[(size_t)i * (B * NO * DE)];
    s += __shfl_xor(s, 1);
    s += __shfl_xor(s, 2);        // full tile sum, all q lanes

    float nsq = s * s;
#pragma unroll
    for (int msk = 4; msk <= 32; msk <<= 1) nsq += __shfl_xor(nsq, msk);
    const float nrm   = sqrtf(nsq);
    const float scale = nrm / (1.f + nsq);
    const float val   = s * scale;

    if (q == 0) {
        out[g]  = val;                               // (B,NO,DE)
        vsum[g] = accum ? (vsum[g] + val) : val;
    }
}

extern "C" void kernel_launch(void* const* d_in, const int* in_sizes, int n_in,
                              void* d_out, int out_size, void* d_ws, size_t ws_size,
                              hipStream_t stream) {
    const float* u    = (const float*)d_in[0];
    const float* w    = (const float*)d_in[1];   // (N,NO,DI,DE)
    const float* bias = (const float*)d_in[2];   // (N,NO)
    // d_in[3] = r, static 3

    float* wsf    = (float*)d_ws;
    float* s_part = wsf + SP_OFF;
    float* vsum   = wsf + VS_OFF;
    float* ut     = wsf + UT_OFF;
    float* out    = (float*)d_out;

    const int use_ut = (ws_size >= (size_t)(SP_SZ + VS_SZ + UT_SZ) * sizeof(float));

    if (use_ut)
        transpose_kernel<<<dim3(N / 4, B / 64), 256, 0, stream>>>(u, ut);

    for (int it = 0; it < 3; ++it) {
        routing_kernel<<<dim3(NTILES, BGS), THREADS, 0, stream>>>(
            u, ut, w, bias, vsum, s_part, it > 0, use_ut);
        squash_kernel<<<(4 * B * NO * DE) / 256, 256, 0, stream>>>(
            s_part, vsum, out, it > 0);
    }
}

// Round 5
// 372.109 us; speedup vs baseline: 1.4862x; 1.4862x over previous
//
#include <hip/hip_runtime.h>

// Capsule dynamic routing — b-on-lanes / o-on-waves, VECTOR-path weights v2.
// u_i:(B,N,DI) f32, w:(1,N,NO,DI,DE) f32, bias:(N,NO,1) f32, r=3.
// Identity: logits_r = u_ji . vsum (vsum = running sum of v; u_ji includes
// bias so the bias term folds in).
// R11: R4 post-mortem — asm pointer laundering caused scratch spills
//   (WRITE 221MB, VGPR 40). Same goal, safe mechanism: runtime vzero kernarg,
//   lz = lane & vzero (==0, unprovable by compiler) added to weight/bias
//   offsets. Divergence analysis -> global_load_dwordx4 broadcast loads on
//   the vector L1 path (1 TA request/wave, counted-vmcnt pipelined) instead
//   of K$-miss-serialized s_loads (~180 lines x ~70cy per CU-n-step = the
//   43us wall in R1/R2; LDS variant R3 hit the same wall on the LDS pipe).
//   Everything else identical to R2 (best: 43us/launch).

#define B    256
#define N    1152
#define NO   10
#define DI   8
#define DE   16
#define NTILE   8
#define NTILES  144    // N / NTILE
#define BG      64     // b per block (= lanes per wave)
#define BGS     4      // B / BG
#define THREADS 640    // 10 waves, o = wave id

// ws layout (floats)
#define SP_OFF 0
#define SP_SZ  (NTILES * B * NO * DE)   // 5,898,240
#define VS_OFF (SP_OFF + SP_SZ)
#define VS_SZ  (B * NO * DE)            // 40,960
#define UT_OFF (VS_OFF + VS_SZ)
#define UT_SZ  (2 * N * B * 4)          // 2,359,296 (= B*N*DI)

// ---------------------------------------------------------------------------
// One-time transpose: u (B,N,8) -> ut[((n*2+h)*B + b)*4 + j] = u[b][n][h*4+j]
// ---------------------------------------------------------------------------
__global__ __launch_bounds__(256)
void transpose_kernel(const float* __restrict__ u, float* __restrict__ ut) {
    const int lane = threadIdx.x & 63;
    const int wv   = threadIdx.x >> 6;           // 0..3 -> n offset
    const int n    = blockIdx.x * 4 + wv;
    const int b    = blockIdx.y * 64 + lane;
    const float* up = u + ((size_t)b * N + n) * DI;
    const float4 a0 = *(const float4*)up;
    const float4 a1 = *(const float4*)(up + 4);
    *(float4*)(ut + ((size_t)(n * 2 + 0) * B + b) * 4) = a0;
    *(float4*)(ut + ((size_t)(n * 2 + 1) * B + b) * 4) = a1;
}

// ---------------------------------------------------------------------------
// Routing pass. Grid: (144 n-tiles, 4 b-groups) x 640 threads (10 waves).
// ---------------------------------------------------------------------------
__global__ __launch_bounds__(THREADS, 4)
void routing_kernel(const float* __restrict__ u,
                    const float* __restrict__ ut,
                    const float* __restrict__ w,
                    const float* __restrict__ bias,
                    const float* __restrict__ vsum,
                    float* __restrict__ s_part,
                    const int has_v,
                    const int use_ut,
                    const int vzero) {
    __shared__ float lgx[2][NO][BG];            // 5 KB double-buffered exchange
    const int tid  = threadIdx.x;
    const int lane = tid & 63;
    const int wv   = __builtin_amdgcn_readfirstlane(tid >> 6);  // 0..9, uniform
    const int o    = wv;                         // one output capsule per wave
    const int b    = blockIdx.y * BG + lane;
    const int n0   = blockIdx.x * NTILE;
    // lz == 0 at runtime (vzero == 0), but the compiler cannot prove it:
    // adding it to an offset makes the address formally divergent -> loads
    // are lowered to global_load_dwordx4 on the vector path (TA broadcasts
    // the same-address access), NOT K$-serialized s_loads.
    const int lz   = lane & vzero;

    // Bias for this wave's o, all 8 n of the tile — broadcast vector loads,
    // hoisted out of the n loop.
    float bvs[NTILE];
#pragma unroll
    for (int i = 0; i < NTILE; ++i)
        bvs[i] = bias[(n0 + i) * NO + o + lz];

    // vsum fragment for this thread's (b, o), full e — loop-invariant
    float4 vv[4];
#pragma unroll
    for (int eq = 0; eq < 4; ++eq)
        vv[eq] = make_float4(0.f, 0.f, 0.f, 0.f);
    if (has_v) {
#pragma unroll
        for (int eq = 0; eq < 4; ++eq)
            vv[eq] = *(const float4*)(vsum + ((size_t)b * NO + o) * DE + eq * 4);
    }

    float4 acc[4];
#pragma unroll
    for (int eq = 0; eq < 4; ++eq)
        acc[eq] = make_float4(0.f, 0.f, 0.f, 0.f);

    for (int i = 0; i < NTILE; ++i) {
        const int n = n0 + i;

        // u row for lane's b — coalesced from ut (1KB/wave/instr), or legacy gather
        float4 u0, u1;
        if (use_ut) {
            const float* up = ut + ((size_t)(n * 2) * B + b) * 4;
            u0 = *(const float4*)up;
            u1 = *(const float4*)(up + B * 4);
        } else {
            const float* up = u + ((size_t)b * N + n) * DI;
            u0 = *(const float4*)up;
            u1 = *(const float4*)(up + 4);
        }
        const float ur[DI] = {u0.x, u0.y, u0.z, u0.w, u1.x, u1.y, u1.z, u1.w};

        // u_ji for this wave's o, all 16 e. Weights via broadcast VECTOR
        // loads (lz makes the address formally divergent; same addr at
        // runtime -> 1 L1 request/wave, vmcnt-pipelined across unrolled d).
        const float* wp = w + ((size_t)n * NO + o) * (DI * DE) + lz;
        const float bv = bvs[i];
        float4 uji[4];
#pragma unroll
        for (int eq = 0; eq < 4; ++eq)
            uji[eq] = make_float4(bv, bv, bv, bv);
#pragma unroll
        for (int d = 0; d < DI; ++d) {
#pragma unroll
            for (int eq = 0; eq < 4; ++eq) {
                const float4 w4 = *(const float4*)(wp + d * DE + eq * 4);
                uji[eq].x += ur[d] * w4.x;
                uji[eq].y += ur[d] * w4.y;
                uji[eq].z += ur[d] * w4.z;
                uji[eq].w += ur[d] * w4.w;
            }
        }

        float c;
        if (has_v) {
            const int pb = i & 1;
            // logit: full-e dot in-thread, exchange via LDS for the softmax
            float lg = 0.f;
#pragma unroll
            for (int eq = 0; eq < 4; ++eq)
                lg += uji[eq].x * vv[eq].x + uji[eq].y * vv[eq].y
                    + uji[eq].z * vv[eq].z + uji[eq].w * vv[eq].w;
            lgx[pb][o][lane] = lg;
            __syncthreads();
            float l[NO];
#pragma unroll
            for (int oo = 0; oo < NO; ++oo) l[oo] = lgx[pb][oo][lane];
            // no second barrier: buffer pb is next written at iter i+2, which
            // is separated from these reads by the barrier at iter i+1.

            float m = l[0];
#pragma unroll
            for (int oo = 1; oo < NO; ++oo) m = fmaxf(m, l[oo]);
            float sum = 0.f;
#pragma unroll
            for (int oo = 0; oo < NO; ++oo) { l[oo] = __expf(l[oo] - m); sum += l[oo]; }
            c = l[o] / sum;
        } else {
            c = 0.1f;   // softmax of zeros
        }

#pragma unroll
        for (int eq = 0; eq < 4; ++eq) {
            acc[eq].x += c * uji[eq].x;
            acc[eq].y += c * uji[eq].y;
            acc[eq].z += c * uji[eq].z;
            acc[eq].w += c * uji[eq].w;
        }
    }

    // s_part[tile][b][o][e] — same layout squash already expects
    float* sp = s_part + (((size_t)blockIdx.x * B + b) * NO + o) * DE;
#pragma unroll
    for (int eq = 0; eq < 4; ++eq)
        *(float4*)(sp + eq * 4) = acc[eq];
}

// ---------------------------------------------------------------------------
// Squash (unchanged — proven): s = sum_tiles s_part;
// v = ||s||/(1+||s||^2)*s; out = v; vsum += v. 4 threads/element (36 tiles ea).
// ---------------------------------------------------------------------------
__global__ __launch_bounds__(256)
void squash_kernel(const float* __restrict__ s_part,
                   float* __restrict__ vsum,
                   float* __restrict__ out,
                   const int accum) {
    const int t0 = blockIdx.x * 256 + threadIdx.x;   // < 4*40960
    const int q  = t0 & 3;
    const int g  = t0 >> 2;

    float s = 0.f;
    const float* sp = s_part + (size_t)(q * 36) * (B * NO * DE) + g;
#pragma unroll 9
    for (int i = 0; i < 36; ++i)
        s += sp[(size_t)i * (B * NO * DE)];
    s += __shfl_xor(s, 1);
    s += __shfl_xor(s, 2);        // full tile sum, all q lanes

    float nsq = s * s;
#pragma unroll
    for (int msk = 4; msk <= 32; msk <<= 1) nsq += __shfl_xor(nsq, msk);
    const float nrm   = sqrtf(nsq);
    const float scale = nrm / (1.f + nsq);
    const float val   = s * scale;

    if (q == 0) {
        out[g]  = val;                               // (B,NO,DE)
        vsum[g] = accum ? (vsum[g] + val) : val;
    }
}

extern "C" void kernel_launch(void* const* d_in, const int* in_sizes, int n_in,
                              void* d_out, int out_size, void* d_ws, size_t ws_size,
                              hipStream_t stream) {
    const float* u    = (const float*)d_in[0];
    const float* w    = (const float*)d_in[1];   // (N,NO,DI,DE)
    const float* bias = (const float*)d_in[2];   // (N,NO)
    // d_in[3] = r, static 3

    float* wsf    = (float*)d_ws;
    float* s_part = wsf + SP_OFF;
    float* vsum   = wsf + VS_OFF;
    float* ut     = wsf + UT_OFF;
    float* out    = (float*)d_out;

    const int use_ut = (ws_size >= (size_t)(SP_SZ + VS_SZ + UT_SZ) * sizeof(float));
    const int vzero  = (int)(ws_size >> 60);     // always 0 at runtime; opaque

    if (use_ut)
        transpose_kernel<<<dim3(N / 4, B / 64), 256, 0, stream>>>(u, ut);

    for (int it = 0; it < 3; ++it) {
        routing_kernel<<<dim3(NTILES, BGS), THREADS, 0, stream>>>(
            u, ut, w, bias, vsum, s_part, it > 0, use_ut, vzero);
        squash_kernel<<<(4 * B * NO * DE) / 256, 256, 0, stream>>>(
            s_part, vsum, out, it > 0);
    }
}

// Round 6
// 181.700 us; speedup vs baseline: 3.0437x; 2.0479x over previous
//
#include <hip/hip_runtime.h>

// Capsule dynamic routing — b-on-lanes / o-on-waves, scalar-path weights.
// u_i:(B,N,DI) f32, w:(1,N,NO,DI,DE) f32, bias:(N,NO,1) f32, r=3.
// Identity: logits_r = u_ji . vsum (u_ji includes bias so bias folds in).
// R12: R5 proved vector-broadcast loads duplicate bytes 64x into RFs (105us);
//   scalar K$ path is byte-optimal (R2, 43us) and its wall is MISS-SERVICE
//   throughput (~180 streaming lines/CU/n-step @ ~60cy) plus 1.33x block
//   imbalance (576 blocks / 256 CU). Fix, keeping the scalar mechanism:
//   (1) 2 b per thread -> each fetched weight feeds 2x FMAs (lines/work /2);
//   (2) NTILE=9, NTILES=128, grid=256 -> exactly 1 block/CU, zero imbalance;
//   (3) XCD swizzle: the 2 same-tile blocks get ids == mod 8 -> same XCD L2
//       (one fill per tile, lower miss latency).

#define B    256
#define N    1152
#define NO   10
#define DI   8
#define DE   16
#define NTILE   9
#define NTILES  128    // N / NTILE
#define BPT     2      // b per thread
#define BG      128    // b per block
#define BGS     2      // B / BG
#define THREADS 640    // 10 waves, o = wave id

// ws layout (floats)
#define SP_OFF 0
#define SP_SZ  (NTILES * B * NO * DE)   // 5,242,880
#define VS_OFF (SP_OFF + SP_SZ)
#define VS_SZ  (B * NO * DE)            // 40,960
#define UT_OFF (VS_OFF + VS_SZ)
#define UT_SZ  (2 * N * B * 4)          // 2,359,296 (= B*N*DI)

// ---------------------------------------------------------------------------
// One-time transpose: u (B,N,8) -> ut[((n*2+h)*B + b)*4 + j] = u[b][n][h*4+j]
// ---------------------------------------------------------------------------
__global__ __launch_bounds__(256)
void transpose_kernel(const float* __restrict__ u, float* __restrict__ ut) {
    const int lane = threadIdx.x & 63;
    const int wv   = threadIdx.x >> 6;           // 0..3 -> n offset
    const int n    = blockIdx.x * 4 + wv;
    const int b    = blockIdx.y * 64 + lane;
    const float* up = u + ((size_t)b * N + n) * DI;
    const float4 a0 = *(const float4*)up;
    const float4 a1 = *(const float4*)(up + 4);
    *(float4*)(ut + ((size_t)(n * 2 + 0) * B + b) * 4) = a0;
    *(float4*)(ut + ((size_t)(n * 2 + 1) * B + b) * 4) = a1;
}

// ---------------------------------------------------------------------------
// Routing pass. Grid: 256 blocks x 640 threads (10 waves). 1 block/CU.
// Block id encodes (tile t 0..127, b-group g 0..1) such that the two blocks
// of a tile share id mod 8 (-> same XCD under round-robin dispatch):
//   id = (t&7) + 8*((t>>3) + 16*g)
// ---------------------------------------------------------------------------
__global__ __launch_bounds__(THREADS, 3)
void routing_kernel(const float* __restrict__ u,
                    const float* __restrict__ ut,
                    const float* __restrict__ w,
                    const float* __restrict__ bias,
                    const float* __restrict__ vsum,
                    float* __restrict__ s_part,
                    const int has_v,
                    const int use_ut) {
    __shared__ float lgx[2][NO][BG];            // 10 KB double-buffered exchange
    const int tid  = threadIdx.x;
    const int lane = tid & 63;
    const int wv   = __builtin_amdgcn_readfirstlane(tid >> 6);  // 0..9, uniform
    const int o    = wv;                         // one output capsule per wave

    const int id   = blockIdx.x;
    const int xcd  = id & 7;
    const int s    = id >> 3;                    // 0..31
    const int g    = s >> 4;                     // 0..1  (b-group)
    const int t    = ((s & 15) << 3) | xcd;      // 0..127 (tile)
    const int n0   = t * NTILE;
    const int bb   = g * BG;                     // block's b base

    // Bias for this wave's o, all 9 n of the tile (scalar path, ~2 lines).
    float bvs[NTILE];
#pragma unroll
    for (int i = 0; i < NTILE; ++i)
        bvs[i] = bias[(n0 + i) * NO + o];

    // vsum fragments for this thread's 2 b values — loop-invariant
    float4 vv[BPT][4];
#pragma unroll
    for (int bi = 0; bi < BPT; ++bi)
#pragma unroll
        for (int eq = 0; eq < 4; ++eq)
            vv[bi][eq] = make_float4(0.f, 0.f, 0.f, 0.f);
    if (has_v) {
#pragma unroll
        for (int bi = 0; bi < BPT; ++bi)
#pragma unroll
            for (int eq = 0; eq < 4; ++eq)
                vv[bi][eq] = *(const float4*)(vsum +
                    ((size_t)(bb + bi * 64 + lane) * NO + o) * DE + eq * 4);
    }

    float4 acc[BPT][4];
#pragma unroll
    for (int bi = 0; bi < BPT; ++bi)
#pragma unroll
        for (int eq = 0; eq < 4; ++eq)
            acc[bi][eq] = make_float4(0.f, 0.f, 0.f, 0.f);

    for (int i = 0; i < NTILE; ++i) {
        const int n = n0 + i;

        // u rows for this thread's 2 b — coalesced from ut, or legacy gather
        float ur[BPT][DI];
#pragma unroll
        for (int bi = 0; bi < BPT; ++bi) {
            const int b = bb + bi * 64 + lane;
            float4 u0, u1;
            if (use_ut) {
                const float* up = ut + ((size_t)(n * 2) * B + b) * 4;
                u0 = *(const float4*)up;
                u1 = *(const float4*)(up + B * 4);
            } else {
                const float* up = u + ((size_t)b * N + n) * DI;
                u0 = *(const float4*)up;
                u1 = *(const float4*)(up + 4);
            }
            ur[bi][0] = u0.x; ur[bi][1] = u0.y; ur[bi][2] = u0.z; ur[bi][3] = u0.w;
            ur[bi][4] = u1.x; ur[bi][5] = u1.y; ur[bi][6] = u1.z; ur[bi][7] = u1.w;
        }

        // u_ji for this wave's o, all 16 e, both b — weights wave-uniform
        // (scalar s_load path); each fetched weight feeds BPT FMAs.
        const float* wp = w + ((size_t)n * NO + o) * (DI * DE);
        const float bv = bvs[i];
        float4 uji[BPT][4];
#pragma unroll
        for (int bi = 0; bi < BPT; ++bi)
#pragma unroll
            for (int eq = 0; eq < 4; ++eq)
                uji[bi][eq] = make_float4(bv, bv, bv, bv);
#pragma unroll
        for (int d = 0; d < DI; ++d) {
#pragma unroll
            for (int eq = 0; eq < 4; ++eq) {
                const float4 w4 = *(const float4*)(wp + d * DE + eq * 4);
#pragma unroll
                for (int bi = 0; bi < BPT; ++bi) {
                    uji[bi][eq].x += ur[bi][d] * w4.x;
                    uji[bi][eq].y += ur[bi][d] * w4.y;
                    uji[bi][eq].z += ur[bi][d] * w4.z;
                    uji[bi][eq].w += ur[bi][d] * w4.w;
                }
            }
        }

        float c[BPT];
        if (has_v) {
            const int pb = i & 1;
            // logits: full-e dot in-thread, exchange via LDS for the softmax
#pragma unroll
            for (int bi = 0; bi < BPT; ++bi) {
                float lg = 0.f;
#pragma unroll
                for (int eq = 0; eq < 4; ++eq)
                    lg += uji[bi][eq].x * vv[bi][eq].x + uji[bi][eq].y * vv[bi][eq].y
                        + uji[bi][eq].z * vv[bi][eq].z + uji[bi][eq].w * vv[bi][eq].w;
                lgx[pb][o][bi * 64 + lane] = lg;
            }
            __syncthreads();
            // sequential per-b softmax (keeps live range small)
#pragma unroll
            for (int bi = 0; bi < BPT; ++bi) {
                float l[NO];
#pragma unroll
                for (int oo = 0; oo < NO; ++oo) l[oo] = lgx[pb][oo][bi * 64 + lane];
                float m = l[0];
#pragma unroll
                for (int oo = 1; oo < NO; ++oo) m = fmaxf(m, l[oo]);
                float sum = 0.f;
#pragma unroll
                for (int oo = 0; oo < NO; ++oo) { l[oo] = __expf(l[oo] - m); sum += l[oo]; }
                c[bi] = l[o] / sum;
            }
            // no second barrier: buffer pb is next written at iter i+2, which
            // is separated from these reads by the barrier at iter i+1.
        } else {
            c[0] = 0.1f; c[1] = 0.1f;   // softmax of zeros
        }

#pragma unroll
        for (int bi = 0; bi < BPT; ++bi)
#pragma unroll
            for (int eq = 0; eq < 4; ++eq) {
                acc[bi][eq].x += c[bi] * uji[bi][eq].x;
                acc[bi][eq].y += c[bi] * uji[bi][eq].y;
                acc[bi][eq].z += c[bi] * uji[bi][eq].z;
                acc[bi][eq].w += c[bi] * uji[bi][eq].w;
            }
    }

    // s_part[tile][b][o][e] — same layout squash expects
#pragma unroll
    for (int bi = 0; bi < BPT; ++bi) {
        float* sp = s_part + (((size_t)t * B + bb + bi * 64 + lane) * NO + o) * DE;
#pragma unroll
        for (int eq = 0; eq < 4; ++eq)
            *(float4*)(sp + eq * 4) = acc[bi][eq];
    }
}

// ---------------------------------------------------------------------------
// Squash: s = sum_tiles s_part; v = ||s||/(1+||s||^2)*s; out = v; vsum += v.
// 4 threads/element, 32 tiles each (NTILES=128).
// ---------------------------------------------------------------------------
__global__ __launch_bounds__(256)
void squash_kernel(const float* __restrict__ s_part,
                   float* __restrict__ vsum,
                   float* __restrict__ out,
                   const int accum) {
    const int t0 = blockIdx.x * 256 + threadIdx.x;   // < 4*40960
    const int q  = t0 & 3;
    const int g  = t0 >> 2;

    float s = 0.f;
    const float* sp = s_part + (size_t)(q * 32) * (B * NO * DE) + g;
#pragma unroll 8
    for (int i = 0; i < 32; ++i)
        s += sp[(size_t)i * (B * NO * DE)];
    s += __shfl_xor(s, 1);
    s += __shfl_xor(s, 2);        // full tile sum, all q lanes

    float nsq = s * s;
#pragma unroll
    for (int msk = 4; msk <= 32; msk <<= 1) nsq += __shfl_xor(nsq, msk);
    const float nrm   = sqrtf(nsq);
    const float scale = nrm / (1.f + nsq);
    const float val   = s * scale;

    if (q == 0) {
        out[g]  = val;                               // (B,NO,DE)
        vsum[g] = accum ? (vsum[g] + val) : val;
    }
}

extern "C" void kernel_launch(void* const* d_in, const int* in_sizes, int n_in,
                              void* d_out, int out_size, void* d_ws, size_t ws_size,
                              hipStream_t stream) {
    const float* u    = (const float*)d_in[0];
    const float* w    = (const float*)d_in[1];   // (N,NO,DI,DE)
    const float* bias = (const float*)d_in[2];   // (N,NO)
    // d_in[3] = r, static 3

    float* wsf    = (float*)d_ws;
    float* s_part = wsf + SP_OFF;
    float* vsum   = wsf + VS_OFF;
    float* ut     = wsf + UT_OFF;
    float* out    = (float*)d_out;

    const int use_ut = (ws_size >= (size_t)(SP_SZ + VS_SZ + UT_SZ) * sizeof(float));

    if (use_ut)
        transpose_kernel<<<dim3(N / 4, B / 64), 256, 0, stream>>>(u, ut);

    for (int it = 0; it < 3; ++it) {
        routing_kernel<<<NTILES * BGS, THREADS, 0, stream>>>(
            u, ut, w, bias, vsum, s_part, it > 0, use_ut);
        squash_kernel<<<(4 * B * NO * DE) / 256, 256, 0, stream>>>(
            s_part, vsum, out, it > 0);
    }
}